// Round 6
// baseline (120.514 us; speedup 1.0000x reference)
//
#include <hip/hip_runtime.h>
#include <math.h>

#define NBINS 15
#define SLOT_STRIDE 48          // 45 doubles used per block slot, padded
#define GRID 2048
#define BLOCK 256

// One wave handles EIGHT rows: segment s = lane>>3 owns row group*8+s,
// lane t = lane&7 owns 16 contiguous columns (4x float4 loads).
// Segmented reductions use xor-shuffles with offsets 4,2,1 (stay in-segment).
// accuracy = (logits[row][label] == rowmax)  -- no argmax tracking needed.
// conf = exp(m) / sum(exp(x)): exps are independent of the max-reduce chain.
//
// Hot loop is the proven round-2 code (101 us e2e). Epilogue: PLAIN stores
// into a private per-block slot (deterministic full overwrite -> no memset
// node, no contended f64 global atomics).
// LESSONS (measured): __builtin_nontemporal_load = 5x regression (bypasses
// L2 path, 598 GB/s). Per-block __threadfence fusion = 4-5x regression (L2
// writeback storm). Do not reintroduce either.
__global__ __launch_bounds__(BLOCK) void ece_main(
    const float* __restrict__ logits,
    const int*   __restrict__ labels,
    int n_groups,                      // n_rows / 8
    double* __restrict__ g_part)       // [GRID][SLOT_STRIDE]: cnt|sumc|suma
{
    __shared__ float    s_sumc[NBINS];
    __shared__ float    s_suma[NBINS];
    __shared__ unsigned s_cnt[NBINS];

    const int tid = threadIdx.x;
    if (tid < NBINS) { s_sumc[tid] = 0.f; s_suma[tid] = 0.f; s_cnt[tid] = 0u; }
    __syncthreads();

    const int lane = tid & 63;
    const int seg  = lane >> 3;        // row within the 8-row group
    const int t    = lane & 7;         // 16-column chunk within the row
    const int wave_global = blockIdx.x * (BLOCK >> 6) + (tid >> 6);
    const int n_waves     = GRID * (BLOCK >> 6);

    for (int g = wave_global; g < n_groups; g += n_waves) {
        const int row = g * 8 + seg;
        const float* rp = logits + ((size_t)row << 7) + (t << 4);
        const float4 v0 = *reinterpret_cast<const float4*>(rp);
        const float4 v1 = *reinterpret_cast<const float4*>(rp + 4);
        const float4 v2 = *reinterpret_cast<const float4*>(rp + 8);
        const float4 v3 = *reinterpret_cast<const float4*>(rp + 12);
        const int lab = labels[row];                       // 8 addrs, 32B span

        // lane-local max over 16 (tree)
        float a0 = fmaxf(fmaxf(v0.x, v0.y), fmaxf(v0.z, v0.w));
        float a1 = fmaxf(fmaxf(v1.x, v1.y), fmaxf(v1.z, v1.w));
        float a2 = fmaxf(fmaxf(v2.x, v2.y), fmaxf(v2.z, v2.w));
        float a3 = fmaxf(fmaxf(v3.x, v3.y), fmaxf(v3.z, v3.w));
        float m  = fmaxf(fmaxf(a0, a1), fmaxf(a2, a3));

        // lane-local sum of exp(x) (independent of m -> parallel dep chains)
        float e0 = __expf(v0.x) + __expf(v0.y) + __expf(v0.z) + __expf(v0.w);
        float e1 = __expf(v1.x) + __expf(v1.y) + __expf(v1.z) + __expf(v1.w);
        float e2 = __expf(v2.x) + __expf(v2.y) + __expf(v2.z) + __expf(v2.w);
        float e3 = __expf(v3.x) + __expf(v3.y) + __expf(v3.z) + __expf(v3.w);
        float p  = (e0 + e1) + (e2 + e3);

        // the label's logit (L1/L2 hit: same lines the wave just fetched)
        const float vlab = logits[((size_t)row << 7) + lab];

        // segmented 8-lane reductions
        #pragma unroll
        for (int off = 4; off; off >>= 1) {
            m = fmaxf(m, __shfl_xor(m, off, 64));
            p += __shfl_xor(p, off, 64);
        }

        if (t == 0) {
            const float conf = __expf(m) / p;              // = max softmax
            const float acc  = (vlab == m) ? 1.0f : 0.0f;  // pred == label
            int bin = (int)ceilf(conf * 15.0f) - 1;        // bin k: (k/15,(k+1)/15]
            bin = bin < 0 ? 0 : (bin > NBINS - 1 ? NBINS - 1 : bin);
            atomicAdd(&s_cnt[bin], 1u);
            atomicAdd(&s_sumc[bin], conf);
            atomicAdd(&s_suma[bin], acc);
        }
    }

    __syncthreads();
    if (tid < 3 * NBINS) {
        const double val = (tid < NBINS)     ? (double)s_cnt[tid]
                         : (tid < 2 * NBINS) ? (double)s_sumc[tid - NBINS]
                                             : (double)s_suma[tid - 2 * NBINS];
        g_part[(size_t)blockIdx.x * SLOT_STRIDE + tid] = val;   // private slot
    }
}

__global__ __launch_bounds__(1024) void ece_final(
    const double* __restrict__ g_part,
    float* __restrict__ out, double inv_n)
{
    __shared__ double s_fin[3 * NBINS];
    const int tid = threadIdx.x;
    if (tid < 3 * NBINS) s_fin[tid] = 0.0;
    __syncthreads();

    const int c  = tid % 45;
    const int r  = tid / 45;           // 0..22
    const int nr = 1024 / 45;          // 22 threads per column
    if (r < nr) {
        double acc = 0.0;
        for (int k = r; k < GRID; k += nr)
            acc += g_part[(size_t)k * SLOT_STRIDE + c];
        atomicAdd(&s_fin[c], acc);     // ds_add_f64
    }
    __syncthreads();

    if (tid == 0) {
        double e = 0.0;
        for (int b = 0; b < NBINS; ++b) {
            const double cnt = s_fin[b];
            if (cnt > 0.0)
                e += fabs(s_fin[NBINS + b] / cnt - s_fin[2 * NBINS + b] / cnt)
                     * (cnt * inv_n);
        }
        out[0] = (float)e;
    }
}

extern "C" void kernel_launch(void* const* d_in, const int* in_sizes, int n_in,
                              void* d_out, int out_size, void* d_ws, size_t ws_size,
                              hipStream_t stream) {
    const float* logits = (const float*)d_in[0];
    const int*   labels = (const int*)d_in[1];
    const int n_rows = in_sizes[1];            // 1048576 (divisible by 8)

    double* g_part = (double*)d_ws;            // GRID*SLOT_STRIDE*8 = 768 KB

    const int n_groups = n_rows >> 3;
    ece_main<<<GRID, BLOCK, 0, stream>>>(logits, labels, n_groups, g_part);
    ece_final<<<1, 1024, 0, stream>>>(g_part, (float*)d_out, 1.0 / (double)n_rows);
}

// Round 7
// 101.467 us; speedup vs baseline: 1.1877x; 1.1877x over previous
//
#include <hip/hip_runtime.h>
#include <math.h>

#define NBINS 15
#define NSLOTS 32   // partial-accumulator slots to spread global atomic contention

// PROVEN CONFIG — 101.0 us e2e, measured twice (rounds 2 and 5).
// One wave handles EIGHT rows: segment s = lane>>3 owns row group*8+s,
// lane t = lane&7 owns 16 contiguous columns (4x float4 loads).
// Segmented reductions use xor-shuffles with offsets 4,2,1 (stay in-segment).
// accuracy = (logits[row][label] == rowmax)  -- no argmax tracking needed.
// conf = exp(m) / sum(exp(x)): exps are independent of the max-reduce chain.
//
// MEASURED LESSONS — do not reintroduce:
//  * __builtin_nontemporal_load: 5x regression (bypasses L2 path, 598 GB/s).
//  * last-block fusion w/ per-block __threadfence: 4-5x regression (L2 storm).
//  * private per-block slots + 1-block 786KB final reduce: +19.5 us (single-CU
//    latency-bound read of cross-XCD-dirty data). The 32-slot L2 atomics hide
//    the cross-block reduction inside the 93-us main stream instead.
__global__ __launch_bounds__(256) void ece_main(
    const float* __restrict__ logits,
    const int*   __restrict__ labels,
    int n_groups,                      // n_rows / 8
    double* __restrict__ g_part)       // [NSLOTS][3*NBINS]: cnt | sumc | suma
{
    __shared__ float    s_sumc[NBINS];
    __shared__ float    s_suma[NBINS];
    __shared__ unsigned s_cnt[NBINS];

    const int tid = threadIdx.x;
    if (tid < NBINS) { s_sumc[tid] = 0.f; s_suma[tid] = 0.f; s_cnt[tid] = 0u; }
    __syncthreads();

    const int lane = tid & 63;
    const int seg  = lane >> 3;        // row within the 8-row group
    const int t    = lane & 7;         // 16-column chunk within the row
    const int wave_global = blockIdx.x * (blockDim.x >> 6) + (tid >> 6);
    const int n_waves     = gridDim.x * (blockDim.x >> 6);

    for (int g = wave_global; g < n_groups; g += n_waves) {
        const int row = g * 8 + seg;
        const float* rp = logits + ((size_t)row << 7) + (t << 4);
        const float4 v0 = *reinterpret_cast<const float4*>(rp);
        const float4 v1 = *reinterpret_cast<const float4*>(rp + 4);
        const float4 v2 = *reinterpret_cast<const float4*>(rp + 8);
        const float4 v3 = *reinterpret_cast<const float4*>(rp + 12);
        const int lab = labels[row];                       // 8 addrs, 32B span

        // lane-local max over 16 (tree)
        float a0 = fmaxf(fmaxf(v0.x, v0.y), fmaxf(v0.z, v0.w));
        float a1 = fmaxf(fmaxf(v1.x, v1.y), fmaxf(v1.z, v1.w));
        float a2 = fmaxf(fmaxf(v2.x, v2.y), fmaxf(v2.z, v2.w));
        float a3 = fmaxf(fmaxf(v3.x, v3.y), fmaxf(v3.z, v3.w));
        float m  = fmaxf(fmaxf(a0, a1), fmaxf(a2, a3));

        // lane-local sum of exp(x) (independent of m -> parallel dep chains)
        float e0 = __expf(v0.x) + __expf(v0.y) + __expf(v0.z) + __expf(v0.w);
        float e1 = __expf(v1.x) + __expf(v1.y) + __expf(v1.z) + __expf(v1.w);
        float e2 = __expf(v2.x) + __expf(v2.y) + __expf(v2.z) + __expf(v2.w);
        float e3 = __expf(v3.x) + __expf(v3.y) + __expf(v3.z) + __expf(v3.w);
        float p  = (e0 + e1) + (e2 + e3);

        // the label's logit (L1/L2 hit: same lines the wave just fetched)
        const float vlab = logits[((size_t)row << 7) + lab];

        // segmented 8-lane reductions
        #pragma unroll
        for (int off = 4; off; off >>= 1) {
            m = fmaxf(m, __shfl_xor(m, off, 64));
            p += __shfl_xor(p, off, 64);
        }

        if (t == 0) {
            const float conf = __expf(m) / p;              // = max softmax
            const float acc  = (vlab == m) ? 1.0f : 0.0f;  // pred == label
            int bin = (int)ceilf(conf * 15.0f) - 1;        // bin k: (k/15,(k+1)/15]
            bin = bin < 0 ? 0 : (bin > NBINS - 1 ? NBINS - 1 : bin);
            atomicAdd(&s_cnt[bin], 1u);
            atomicAdd(&s_sumc[bin], conf);
            atomicAdd(&s_suma[bin], acc);
        }
    }

    __syncthreads();
    if (tid < 3 * NBINS) {
        double val = (tid < NBINS)     ? (double)s_cnt[tid]
                   : (tid < 2 * NBINS) ? (double)s_sumc[tid - NBINS]
                                       : (double)s_suma[tid - 2 * NBINS];
        atomicAdd(&g_part[(size_t)(blockIdx.x & (NSLOTS - 1)) * (3 * NBINS) + tid], val);
    }
}

__global__ void ece_final(const double* __restrict__ g_part,
                          float* __restrict__ out, double inv_n)
{
    __shared__ double s[3 * NBINS];
    const int t = threadIdx.x;
    if (t < 3 * NBINS) {
        double acc = 0.0;
        for (int k = 0; k < NSLOTS; ++k) acc += g_part[k * 3 * NBINS + t];
        s[t] = acc;
    }
    __syncthreads();
    if (t == 0) {
        double e = 0.0;
        for (int b = 0; b < NBINS; ++b) {
            const double c = s[b];
            if (c > 0.0)
                e += fabs(s[NBINS + b] / c - s[2 * NBINS + b] / c) * (c * inv_n);
        }
        out[0] = (float)e;
    }
}

extern "C" void kernel_launch(void* const* d_in, const int* in_sizes, int n_in,
                              void* d_out, int out_size, void* d_ws, size_t ws_size,
                              hipStream_t stream) {
    const float* logits = (const float*)d_in[0];
    const int*   labels = (const int*)d_in[1];
    const int n_rows = in_sizes[1];            // 1048576 (divisible by 8)

    double* g_part = (double*)d_ws;
    hipMemsetAsync(g_part, 0, (size_t)NSLOTS * 3 * NBINS * sizeof(double), stream);

    const int n_groups = n_rows >> 3;
    ece_main<<<2048, 256, 0, stream>>>(logits, labels, n_groups, g_part);
    ece_final<<<1, 64, 0, stream>>>(g_part, (float*)d_out, 1.0 / (double)n_rows);
}